// Round 3
// baseline (336.010 us; speedup 1.0000x reference)
//
#include <hip/hip_runtime.h>

typedef __attribute__((ext_vector_type(4))) float float4v;

// Kernel 1: pib[row,f] = sum_e x[row,e]*W[f,e] + bias[f]
//           pj [row,f] = sum_e x[row,e]*W[f,256+e]
// row = b*256+s in [0,1024), f in [0,256). W is (256,512) row-major fp32.
__global__ __launch_bounds__(256) void gemm_pipj(
    const float* __restrict__ x, const float* __restrict__ W,
    const float* __restrict__ bias,
    float* __restrict__ pib, float* __restrict__ pj) {
    const int row = blockIdx.x;
    const int f = threadIdx.x;
    __shared__ float xs[256];
    xs[f] = x[row * 256 + f];
    __syncthreads();

    const float4v* wr = (const float4v*)(W + (size_t)f * 512);
    float acc0 = 0.f, acc1 = 0.f;
#pragma unroll 8
    for (int e4 = 0; e4 < 64; ++e4) {
        float4v w1 = wr[e4];        // cols e4*4 .. +3        (pi half)
        float4v w2 = wr[e4 + 64];   // cols 256+e4*4 .. +3    (pj half)
        float x0 = xs[e4 * 4 + 0];
        float x1 = xs[e4 * 4 + 1];
        float x2 = xs[e4 * 4 + 2];
        float x3 = xs[e4 * 4 + 3];
        acc0 += x0 * w1.x + x1 * w1.y + x2 * w1.z + x3 * w1.w;
        acc1 += x0 * w2.x + x1 * w2.y + x2 * w2.z + x3 * w2.w;
    }
    pib[row * 256 + f] = acc0 + bias[f];
    pj [row * 256 + f] = acc1;
}

// Kernel 2: out[bi, j, f] = pib[bi, f] + pj[b*256+j, f],  bi = b*256+i.
// blockIdx.x = bi*32 + jg; block covers j in [jg*8, jg*8+8).
// Wave w (t>>6) handles j = jg*8 + 2w + {0,1}; lane covers f0=(t&63)*4.
// pi fragment loaded once per thread, reused for both j. All loads/stores
// are 16B, waves fully coalesced (64 lanes x 16B = 1KB contiguous).
__global__ __launch_bounds__(256) void bcast_add(
    const float* __restrict__ pib, const float* __restrict__ pj,
    float* __restrict__ out) {
    const int bi = blockIdx.x >> 5;      // b*256 + i
    const int jg = blockIdx.x & 31;
    const int t = threadIdx.x;
    const int w = t >> 6;                // wave 0..3
    const int f0 = (t & 63) * 4;
    const int b = bi >> 8;
    const int j0 = jg * 8 + w * 2;

    const float4v a = *(const float4v*)(pib + (size_t)bi * 256 + f0);
    const float4v p0 = *(const float4v*)(pj + ((size_t)(b * 256 + j0)) * 256 + f0);
    const float4v p1 = *(const float4v*)(pj + ((size_t)(b * 256 + j0 + 1)) * 256 + f0);

    const size_t base = (((size_t)bi * 256) + j0) * 256 + f0;
    *(float4v*)(out + base)       = a + p0;
    *(float4v*)(out + base + 256) = a + p1;
}

extern "C" void kernel_launch(void* const* d_in, const int* in_sizes, int n_in,
                              void* d_out, int out_size, void* d_ws, size_t ws_size,
                              hipStream_t stream) {
    const float* x    = (const float*)d_in[0];  // (4,256,256) fp32
    const float* W    = (const float*)d_in[1];  // (256,512)   fp32
    const float* bias = (const float*)d_in[2];  // (256,)      fp32
    float* out = (float*)d_out;                 // (4,256,256,256) fp32

    float* pib = (float*)d_ws;            // 1024*256 fp32 = 1 MiB
    float* pj  = pib + 1024 * 256;        // 1024*256 fp32 = 1 MiB

    gemm_pipj<<<1024, 256, 0, stream>>>(x, W, bias, pib, pj);
    bcast_add<<<4 * 256 * 32, 256, 0, stream>>>(pib, pj, out);
}

// Round 4
// 282.256 us; speedup vs baseline: 1.1904x; 1.1904x over previous
//
#include <hip/hip_runtime.h>

typedef __attribute__((ext_vector_type(4))) float float4v;

// Kernel 1: pib[row,f] = sum_e x[row,e]*W[f,e] + bias[f]
//           pj [row,f] = sum_e x[row,e]*W[f,256+e]
// 4 rows per block (256 blocks): W read once per block -> 128 MB total L2
// traffic instead of 512 MB. Thread f keeps 8 accumulators (4 rows x 2
// halves); W chunks reused across the 4 rows. xs LDS reads are wave-uniform
// (broadcast, conflict-free).
__global__ __launch_bounds__(256) void gemm_pipj(
    const float* __restrict__ x, const float* __restrict__ W,
    const float* __restrict__ bias,
    float* __restrict__ pib, float* __restrict__ pj) {
    const int r0 = blockIdx.x * 4;
    const int f = threadIdx.x;
    __shared__ float xs[4][256];
#pragma unroll
    for (int k = 0; k < 4; ++k)
        xs[k][f] = x[(size_t)(r0 + k) * 256 + f];
    __syncthreads();

    const float4v* wr = (const float4v*)(W + (size_t)f * 512);
    float acc0[4] = {0.f, 0.f, 0.f, 0.f};
    float acc1[4] = {0.f, 0.f, 0.f, 0.f};
#pragma unroll 4
    for (int e4 = 0; e4 < 64; ++e4) {
        float4v w1 = wr[e4];        // cols e4*4..+3       (pi half)
        float4v w2 = wr[e4 + 64];   // cols 256+e4*4..+3   (pj half)
#pragma unroll
        for (int r = 0; r < 4; ++r) {
            float x0 = xs[r][e4 * 4 + 0];
            float x1 = xs[r][e4 * 4 + 1];
            float x2 = xs[r][e4 * 4 + 2];
            float x3 = xs[r][e4 * 4 + 3];
            acc0[r] += x0 * w1.x + x1 * w1.y + x2 * w1.z + x3 * w1.w;
            acc1[r] += x0 * w2.x + x1 * w2.y + x2 * w2.z + x3 * w2.w;
        }
    }
    float bv = bias[f];
#pragma unroll
    for (int r = 0; r < 4; ++r) {
        pib[(size_t)(r0 + r) * 256 + f] = acc0[r] + bv;
        pj [(size_t)(r0 + r) * 256 + f] = acc1[r];
    }
}

// Kernel 2: out[bi, j, f] = pib[bi, f] + pj[b*256+j, f],  bi = b*256+i.
// blockIdx.x = bi*16 + jq; wave w covers j = jq*16 + w*4 + {0..3}; lane
// covers f0=(t&63)*4. One pi load amortized over 4 j's. Output streamed
// with nontemporal stores (268 MB write-once, keep pi/pj L2-resident).
// Every wave store is 64 lanes x 16B = 1 KB contiguous.
__global__ __launch_bounds__(256) void bcast_add(
    const float* __restrict__ pib, const float* __restrict__ pj,
    float* __restrict__ out) {
    const int bi = blockIdx.x >> 4;      // b*256 + i
    const int jq = blockIdx.x & 15;
    const int t = threadIdx.x;
    const int w = t >> 6;                // wave 0..3
    const int f0 = (t & 63) * 4;
    const int b = bi >> 8;
    const int j0 = jq * 16 + w * 4;

    const float4v a = *(const float4v*)(pib + (size_t)bi * 256 + f0);
    const float* pjbase = pj + ((size_t)(b * 256 + j0)) * 256 + f0;
    float* obase = out + (((size_t)bi * 256) + j0) * 256 + f0;
#pragma unroll
    for (int r = 0; r < 4; ++r) {
        float4v p = *(const float4v*)(pjbase + (size_t)r * 256);
        float4v v = a + p;
        __builtin_nontemporal_store(v, (float4v*)(obase + (size_t)r * 256));
    }
}

extern "C" void kernel_launch(void* const* d_in, const int* in_sizes, int n_in,
                              void* d_out, int out_size, void* d_ws, size_t ws_size,
                              hipStream_t stream) {
    const float* x    = (const float*)d_in[0];  // (4,256,256) fp32
    const float* W    = (const float*)d_in[1];  // (256,512)   fp32
    const float* bias = (const float*)d_in[2];  // (256,)      fp32
    float* out = (float*)d_out;                 // (4,256,256,256) fp32

    float* pib = (float*)d_ws;            // 1024*256 fp32 = 1 MiB
    float* pj  = pib + 1024 * 256;        // 1024*256 fp32 = 1 MiB

    gemm_pipj<<<256, 256, 0, stream>>>(x, W, bias, pib, pj);
    bcast_add<<<1024 * 16, 256, 0, stream>>>(pib, pj, out);
}